// Round 1
// 133.032 us; speedup vs baseline: 1.0026x; 1.0026x over previous
//
#include <hip/hip_runtime.h>

#define L 32
#define W 262144              // 2^18
#define NN (L * W)
#define CAP 2048              // cone capacity; expected cone size = 2*31+1 = 63
#define MAXR 40

// Only the dependency cone of node NN-1 matters (~63 nodes expected, depth
// <= 31, typically ~10). BFS-expand top-down (each round = one parallel
// batch of cold random gathers -- latency chain is the floor since the
// harness's 256 MiB poison fill flushes L3 every iteration), then evaluate
// bottom-up in LDS. Single wave (64 lanes).
//
// vs previous version:
//  - slot allocation via __ballot + popcount prefix (wave-uniform register
//    count) instead of serialized same-address LDS atomicAdd
//  - one __syncthreads per BFS round instead of two
//  - round 0 specialized: root id NN-1 is a constant, so its gather issues
//    as the first instruction with no LDS round-trip / init barrier
//  - root eval folded into the final store (saves last eval round + sync)
//
// Node n >= W maps to flat row n - W in child_idx/node_types.
__global__ __launch_bounds__(64) void recnn_cone(
    const float* __restrict__ values,
    const int2*  __restrict__ cidx,    // child_idx as [(L-1)*W] int2
    const int*   __restrict__ ntype,   // node_types  [(L-1)*W]
    const float* __restrict__ w_term,
    const float* __restrict__ w_plus,
    const float* __restrict__ w_minus,
    const float* __restrict__ w_final,
    const float* __restrict__ b_final,
    float* __restrict__ out)
{
    __shared__ int   s_node[CAP];
    __shared__ int   s_type[CAP];   // 0 = leaf (val ready), 1 = plus, 2 = minus
    __shared__ int   s_c0[CAP];     // child slots: s_c0[i], s_c0[i]+1
    __shared__ float s_val[CAP];
    __shared__ int   rb[MAXR];      // round r occupies [rb[r], rb[r+1])

    const int tid = threadIdx.x;

    // ---- round 0: root (always non-terminal). Gather issues immediately. ----
    const int2 rc = cidx[NN - 1 - W];   // first instruction-level work: cold miss starts now
    const int  rt = ntype[NN - 1 - W];

    const float wt  = w_term[0];
    const float wp0 = w_plus[0],  wp1 = w_plus[1];
    const float wm0 = w_minus[0], wm1 = w_minus[1];

    if (tid == 0) {
        s_node[1] = rc.x;
        s_node[2] = rc.y;
        rb[0] = 0; rb[1] = 1; rb[2] = 3;
        // root's type/children stay in registers (rt, slots 1 & 2 fixed)
    }
    __syncthreads();

    // ---- top-down BFS expansion, ballot-based slot allocation ----
    int fs = 1, fe = 3, nr = 1;     // rounds 0 done; round 1 frontier = [1,3)
    int cnt = 3;                    // wave-uniform next free slot
    const unsigned long long lt_mask = (1ull << tid) - 1ull;

    while (fs < fe && nr < 32) {
        for (int base = fs; base < fe; base += 64) {   // uniform bound: all 64 lanes iterate
            const int  i   = base + tid;
            const bool act = i < fe;
            const int  n   = act ? s_node[i] : -1;
            const bool isx = act && (n >= W);
            const unsigned long long mask = __ballot(isx);
            const int slot = cnt + 2 * (int)__popcll(mask & lt_mask);
            if (isx) {
                int2 c  = cidx[n - W];       // random 8B gather (cold, ~900 cy)
                int  ty = ntype[n - W];      // parallel 4B gather
                if (slot + 1 < CAP) {
                    s_node[slot]     = c.x;
                    s_node[slot + 1] = c.y;
                    s_c0[i]   = slot;
                    s_type[i] = ty;
                } else {                     // overflow guard (never expected)
                    s_type[i] = 0;
                    s_val[i]  = 0.0f;
                }
            } else if (act) {                // terminal node
                s_type[i] = 0;
                s_val[i]  = values[n] * wt;  // random 4B gather
            }
            cnt += 2 * (int)__popcll(mask);  // uniform update, no atomics
        }
        const int fe_next = min(cnt, CAP);
        nr++;
        if (tid == 0) rb[nr + 1] = fe_next;
        __syncthreads();                     // single barrier per round
        fs = fe;
        fe = fe_next;
    }

    // ---- bottom-up evaluation (children of round r live in rounds > r) ----
    for (int r = nr - 1; r >= 1; --r) {
        for (int i = rb[r] + tid; i < rb[r + 1]; i += 64) {
            const int ty = s_type[i];
            if (ty != 0) {
                const int   c0 = s_c0[i];
                const float x0 = s_val[c0], x1 = s_val[c0 + 1];
                s_val[i] = (ty == 1) ? fmaf(x0, wp0, x1 * wp1)
                                     : fmaf(x0, wm0, x1 * wm1);
            }
        }
        __syncthreads();
    }

    // root eval fused into the final store (children fixed at slots 1,2)
    if (tid == 0) {
        const float x0 = s_val[1], x1 = s_val[2];
        const float v  = (rt == 1) ? fmaf(x0, wp0, x1 * wp1)
                                   : fmaf(x0, wm0, x1 * wm1);
        out[0] = fmaf(v, w_final[0], b_final[0]);
    }
}

extern "C" void kernel_launch(void* const* d_in, const int* in_sizes, int n_in,
                              void* d_out, int out_size, void* d_ws, size_t ws_size,
                              hipStream_t stream) {
    const float* values     = (const float*)d_in[0];
    const int*   child_idx  = (const int*)d_in[1];   // [L-1, W, 2]
    const int*   node_types = (const int*)d_in[2];   // [L-1, W]
    const float* w_term     = (const float*)d_in[3];
    const float* w_plus     = (const float*)d_in[4];
    const float* w_minus    = (const float*)d_in[5];
    const float* w_final    = (const float*)d_in[6];
    const float* b_final    = (const float*)d_in[7];

    float* out = (float*)d_out;

    recnn_cone<<<1, 64, 0, stream>>>(
        values, (const int2*)child_idx, node_types,
        w_term, w_plus, w_minus, w_final, b_final, out);
}